// Round 22
// baseline (104.686 us; speedup 1.0000x reference)
//
#include <hip/hip_runtime.h>
#include <hip/hip_fp16.h>

#define F1 64
#define F2 32
#define FIN 13
#define BSH 9                 // bucket = dst >> 9  (512 nodes/bucket)
#define BNODES 512
#define TILE 4096             // edges per scatter block (8 per thread)
#define SCT 512               // scatter threads
#define CAPB 8192             // fixed capacity per bucket (mean 6400, sd ~80 -> 22 sigma)
#define SRCMASK 0x7FFFFF      // 23-bit src (N < 8.4M)

typedef unsigned nuint4 __attribute__((ext_vector_type(4)));  // native vec for nt-store

// ---------- init capacity-strided bucket cursors ----------
__global__ void k_initc(int* __restrict__ gcur, int NBK) {
    int i = threadIdx.x + blockIdx.x * blockDim.x;
    if (i < NBK) gcur[i] = i * CAPB;
}

// ---------- partition edges into capacity-strided buckets, packed (ldst<<23|src) ----------
// register-resident edges: one vectorized read pass, histogram + scatter from regs
__global__ void __launch_bounds__(SCT)
k_bscatter(const int* __restrict__ src, const int* __restrict__ dst,
           int* __restrict__ gcur, unsigned* __restrict__ pairs,
           int E, int NBK) {
    __shared__ int lh[256];
    __shared__ int lbase[256];
    int tid = threadIdx.x;
    long t0 = (long)blockIdx.x * TILE;
    int lim = (int)min((long)TILE, (long)E - t0);
    int d[8], s[8];
    int base = tid * 8;
    if (base + 8 <= lim) {
        int4 d0 = *(const int4*)&dst[t0 + base];
        int4 d1 = *(const int4*)&dst[t0 + base + 4];
        int4 s0 = *(const int4*)&src[t0 + base];
        int4 s1 = *(const int4*)&src[t0 + base + 4];
        d[0] = d0.x; d[1] = d0.y; d[2] = d0.z; d[3] = d0.w;
        d[4] = d1.x; d[5] = d1.y; d[6] = d1.z; d[7] = d1.w;
        s[0] = s0.x; s[1] = s0.y; s[2] = s0.z; s[3] = s0.w;
        s[4] = s1.x; s[5] = s1.y; s[6] = s1.z; s[7] = s1.w;
    } else {
#pragma unroll
        for (int k = 0; k < 8; ++k) {
            int i = base + k;
            d[k] = (i < lim) ? dst[t0 + i] : -1;
            s[k] = (i < lim) ? src[t0 + i] : 0;
        }
    }
    for (int i = tid; i < NBK; i += SCT) lh[i] = 0;
    __syncthreads();
#pragma unroll
    for (int k = 0; k < 8; ++k)
        if (d[k] >= 0) atomicAdd(&lh[d[k] >> BSH], 1);
    __syncthreads();
    for (int b = tid; b < NBK; b += SCT) {
        int c = lh[b];
        lbase[b] = c ? atomicAdd(&gcur[b], c) : 0;
    }
    __syncthreads();
#pragma unroll
    for (int k = 0; k < 8; ++k) {
        if (d[k] >= 0) {
            int b = d[k] >> BSH;
            int r = atomicAdd(&lbase[b], 1);   // lbase doubles as cursor
            pairs[r] = ((unsigned)(d[k] & (BNODES - 1)) << 23) | (unsigned)s[k];
        }
    }
}

// ---------- per-bucket counting sort -> csr (strided), rowstart, deg, dinv, fused xn ----------
__global__ void __launch_bounds__(1024)
k_bsort(const unsigned* __restrict__ pairs, const int* __restrict__ gcur,
        const float* __restrict__ x, int* __restrict__ rowstart,
        int* __restrict__ deg, float* __restrict__ dinv, int* __restrict__ csr,
        __half2* __restrict__ xnh, int N) {
    __shared__ int cnt[BNODES];
    __shared__ int lex[BNODES];
    __shared__ int lcur[BNODES];
    __shared__ float dinvl[BNODES];
    __shared__ int lsorted[CAPB];
    int tid = threadIdx.x;
    int bk = blockIdx.x;
    int nodeBase = bk << BSH;
    int st = bk * CAPB;
    int m = gcur[bk] - st;
    if (m > CAPB) m = CAPB;               // safety clamp (impossible at 22 sigma)
    for (int i = tid; i < BNODES; i += 1024) { cnt[i] = 0; lcur[i] = 0; }
    __syncthreads();
    for (int i = tid; i < m; i += 1024)
        atomicAdd(&cnt[pairs[st + i] >> 23], 1);
    __syncthreads();
    if (tid < BNODES) lex[tid] = cnt[tid];
    __syncthreads();
    for (int off = 1; off < BNODES; off <<= 1) {
        int a = 0;
        if (tid < BNODES && tid >= off) a = lex[tid - off];
        __syncthreads();
        if (tid < BNODES) lex[tid] += a;
        __syncthreads();
    }
    if (tid < BNODES) {
        int ex = lex[tid] - cnt[tid];        // exclusive
        int v = nodeBase + tid;
        float dv = rsqrtf((float)(cnt[tid] + 1));
        dinvl[tid] = dv;
        if (v < N) {
            rowstart[v] = st + ex;
            deg[v] = cnt[tid];
            dinv[v] = dv;
        }
        lex[tid] = ex;
    }
    __syncthreads();
    for (int i = tid; i < m; i += 1024) {
        unsigned p = pairs[st + i];
        int ld = p >> 23;
        int r = atomicAdd(&lcur[ld], 1);
        lsorted[lex[ld] + r] = (int)(p & SRCMASK);
    }
    __syncthreads();
    for (int i = tid; i < m; i += 1024) csr[st + i] = lsorted[i];
    // fused xn: xnh[v][cp] = half2(x[v][2cp], x[v][2cp+1]) * dinv, 16 cols 0-pad
    for (int i = tid; i < BNODES * 8; i += 1024) {
        int n = i >> 3, cp = i & 7;
        int v = nodeBase + n;
        if (v < N) {
            float dv = dinvl[n];
            int c0 = 2 * cp, c1 = c0 + 1;
            float a = (c0 < FIN) ? x[(size_t)v * FIN + c0] * dv : 0.f;
            float b = (c1 < FIN) ? x[(size_t)v * FIN + c1] * dv : 0.f;
            xnh[(size_t)v * 8 + cp] = __floats2half2_rn(a, b);
        }
    }
}

__device__ __forceinline__ void acc8(const uint4& u, float4& a, float4& b) {
    float2 f0 = __half22float2(*reinterpret_cast<const __half2*>(&u.x));
    float2 f1 = __half22float2(*reinterpret_cast<const __half2*>(&u.y));
    float2 f2 = __half22float2(*reinterpret_cast<const __half2*>(&u.z));
    float2 f3 = __half22float2(*reinterpret_cast<const __half2*>(&u.w));
    a.x += f0.x; a.y += f0.y; a.z += f1.x; a.w += f1.y;
    b.x += f2.x; b.y += f2.y; b.z += f3.x; b.w += f3.y;
}

__device__ __forceinline__ unsigned packh2(float a, float b) {
    __half2 h = __floats2half2_rn(a, b);
    return *reinterpret_cast<unsigned*>(&h);
}

// ---------- layer1 pure gather, 2 slots x 4-deep: agg1h[v] = (xn[v]+sum xn[src])*dinv ----------
// 512 thr = 128 nodes x (2 slots x 2 lanes); lane reads 16B (8 fp16 cols); slot stride 2
__global__ void __launch_bounds__(512)
k_agg1(const uint4* __restrict__ xnh4, const int* __restrict__ rowstart,
       const int* __restrict__ deg, const float* __restrict__ dinv,
       const int* __restrict__ csr, uint4* __restrict__ agg1h4, int N) {
    int tid = threadIdx.x;
    int ln = tid >> 2;           // local node 0..127
    int slot = (tid >> 1) & 1;   // edge slot 0..1
    int l = tid & 1;             // 16B lane: cols 8l..8l+7
    int v = blockIdx.x * 128 + ln;
    if (v >= N) return;
    int st = rowstart[v];
    int en = st + deg[v];
    float4 accA = make_float4(0.f, 0.f, 0.f, 0.f);
    float4 accB = make_float4(0.f, 0.f, 0.f, 0.f);
    int e = st + slot;
    while (e + 6 < en) {         // 4-deep: 4 independent csr + 4 gathers in flight
        int s0 = csr[e];
        int s1 = csr[e + 2];
        int s2 = csr[e + 4];
        int s3 = csr[e + 6];
        uint4 u0 = xnh4[(size_t)s0 * 2 + l];
        uint4 u1 = xnh4[(size_t)s1 * 2 + l];
        uint4 u2 = xnh4[(size_t)s2 * 2 + l];
        uint4 u3 = xnh4[(size_t)s3 * 2 + l];
        acc8(u0, accA, accB);
        acc8(u1, accA, accB);
        acc8(u2, accA, accB);
        acc8(u3, accA, accB);
        e += 8;
    }
    while (e + 2 < en) {         // 2-deep remainder
        int s0 = csr[e];
        int s1 = csr[e + 2];
        uint4 u0 = xnh4[(size_t)s0 * 2 + l];
        uint4 u1 = xnh4[(size_t)s1 * 2 + l];
        acc8(u0, accA, accB);
        acc8(u1, accA, accB);
        e += 4;
    }
    if (e < en) {
        int s0 = csr[e];
        uint4 u0 = xnh4[(size_t)s0 * 2 + l];
        acc8(u0, accA, accB);
    }
    // reduce 2 slots (slot bit at tid[1])
    accA.x += __shfl_xor(accA.x, 2); accA.y += __shfl_xor(accA.y, 2);
    accA.z += __shfl_xor(accA.z, 2); accA.w += __shfl_xor(accA.w, 2);
    accB.x += __shfl_xor(accB.x, 2); accB.y += __shfl_xor(accB.y, 2);
    accB.z += __shfl_xor(accB.z, 2); accB.w += __shfl_xor(accB.w, 2);
    if (slot == 0) {
        uint4 u = xnh4[(size_t)v * 2 + l];   // self (has one dinv)
        float4 sA = make_float4(0.f, 0.f, 0.f, 0.f);
        float4 sB = make_float4(0.f, 0.f, 0.f, 0.f);
        acc8(u, sA, sB);
        float dv = dinv[v];
        nuint4 o;
        o.x = packh2((sA.x + accA.x) * dv, (sA.y + accA.y) * dv);
        o.y = packh2((sA.z + accA.z) * dv, (sA.w + accA.w) * dv);
        o.z = packh2((sB.x + accB.x) * dv, (sB.y + accB.y) * dv);
        o.w = packh2((sB.z + accB.z) * dv, (sB.w + accB.w) * dv);
        __builtin_nontemporal_store(o, (nuint4*)&agg1h4[(size_t)v * 2 + l]);
    }
}

// ---------- transform: per-node in registers. y2 = (relu(agg1@W1+b1) @ W2) * dinv ----------
__global__ void __launch_bounds__(256)
k_trans(const uint4* __restrict__ agg1h4, const float* __restrict__ W1,
        const float* __restrict__ b1, const float* __restrict__ W2,
        const float* __restrict__ dinv, __half2* __restrict__ y2h, int N) {
    int v = blockIdx.x * 256 + threadIdx.x;
    if (v >= N) return;
    uint4 u0 = agg1h4[(size_t)v * 2];
    uint4 u1 = agg1h4[(size_t)v * 2 + 1];
    float a[16];
    {
        float4 A = make_float4(0.f, 0.f, 0.f, 0.f), B = A;
        acc8(u0, A, B);
        a[0] = A.x; a[1] = A.y; a[2] = A.z; a[3] = A.w;
        a[4] = B.x; a[5] = B.y; a[6] = B.z; a[7] = B.w;
        A = make_float4(0.f, 0.f, 0.f, 0.f); B = A;
        acc8(u1, A, B);
        a[8] = A.x; a[9] = A.y; a[10] = A.z; a[11] = A.w;
        a[12] = B.x; a[13] = B.y; a[14] = B.z; a[15] = B.w;
    }
    float h[F1];
#pragma unroll
    for (int c = 0; c < F1; ++c) {
        float acc = b1[c];
#pragma unroll
        for (int k = 0; k < FIN; ++k) acc += a[k] * W1[k * F1 + c];
        h[c] = fmaxf(acc, 0.f);
    }
    float dv = dinv[v];
    for (int cp = 0; cp < 16; ++cp) {        // rolled: only acc0/acc1 live
        float acc0 = 0.f, acc1 = 0.f;
#pragma unroll
        for (int k = 0; k < F1; ++k) {       // unrolled: h[k] static
            float hv = h[k];
            acc0 += hv * W2[k * F2 + 2 * cp];
            acc1 += hv * W2[k * F2 + 2 * cp + 1];
        }
        y2h[(size_t)v * 16 + cp] = __floats2half2_rn(acc0 * dv, acc1 * dv);
    }
}

// ---------- fused layer2 aggregate + mean-pool + MLP: one block per graph ----------
// 1024 thr = 128 node-groups x (2 slots x 4 lanes); lane reads 16B; slot stride 2
__global__ void __launch_bounds__(1024)
k_gagg2(const uint4* __restrict__ y2h4, const int* __restrict__ rowstart,
        const int* __restrict__ deg, const float* __restrict__ dinv,
        const int* __restrict__ csr, const float* __restrict__ b2,
        const float* __restrict__ fc1w, const float* __restrict__ fc1b,
        const float* __restrict__ fc2w, const float* __restrict__ fc2b,
        const int* __restrict__ batch, float* __restrict__ out, int N, int G) {
    __shared__ int bounds[2];
    __shared__ float part[128][33];   // pad 33: conflict-free column reduce
    __shared__ float gvec[F2];
    __shared__ float h1[F2];
    int tid = threadIdx.x;
    int g = blockIdx.x;
    if (tid < 2) {
        int target = g + tid;         // lower_bound(batch, target)
        int lo = 0, hi = N;
        while (lo < hi) {
            int mid = (lo + hi) >> 1;
            if (batch[mid] < target) lo = mid + 1; else hi = mid;
        }
        bounds[tid] = lo;
    }
    __syncthreads();
    int st = bounds[0], en = bounds[1];
    int ln = tid >> 3;            // node-group 0..127
    int slot = (tid >> 2) & 1;    // edge slot 0..1
    int l = tid & 3;              // 16B lane: cols 8l..8l+7
    float4 pA = make_float4(0.f, 0.f, 0.f, 0.f);
    float4 pB = make_float4(0.f, 0.f, 0.f, 0.f);
    for (int v = st + ln; v < en; v += 128) {
        int es = rowstart[v];
        int ee = es + deg[v];
        float4 accA = make_float4(0.f, 0.f, 0.f, 0.f);
        float4 accB = make_float4(0.f, 0.f, 0.f, 0.f);
        int e = es + slot;
        while (e + 6 < ee) {      // 4-deep
            int s0 = csr[e];
            int s1 = csr[e + 2];
            int s2 = csr[e + 4];
            int s3 = csr[e + 6];
            uint4 u0 = y2h4[(size_t)s0 * 4 + l];
            uint4 u1 = y2h4[(size_t)s1 * 4 + l];
            uint4 u2 = y2h4[(size_t)s2 * 4 + l];
            uint4 u3 = y2h4[(size_t)s3 * 4 + l];
            acc8(u0, accA, accB);
            acc8(u1, accA, accB);
            acc8(u2, accA, accB);
            acc8(u3, accA, accB);
            e += 8;
        }
        while (e + 2 < ee) {      // 2-deep remainder
            int s0 = csr[e];
            int s1 = csr[e + 2];
            uint4 u0 = y2h4[(size_t)s0 * 4 + l];
            uint4 u1 = y2h4[(size_t)s1 * 4 + l];
            acc8(u0, accA, accB);
            acc8(u1, accA, accB);
            e += 4;
        }
        if (e < ee) {
            int s0 = csr[e];
            uint4 u0 = y2h4[(size_t)s0 * 4 + l];
            acc8(u0, accA, accB);
        }
        // reduce 2 slots (slot bit at tid[2])
        accA.x += __shfl_xor(accA.x, 4); accA.y += __shfl_xor(accA.y, 4);
        accA.z += __shfl_xor(accA.z, 4); accA.w += __shfl_xor(accA.w, 4);
        accB.x += __shfl_xor(accB.x, 4); accB.y += __shfl_xor(accB.y, 4);
        accB.z += __shfl_xor(accB.z, 4); accB.w += __shfl_xor(accB.w, 4);
        if (slot == 0) {
            uint4 u = y2h4[(size_t)v * 4 + l];
            float4 sA = make_float4(0.f, 0.f, 0.f, 0.f);
            float4 sB = make_float4(0.f, 0.f, 0.f, 0.f);
            acc8(u, sA, sB);
            float dv = dinv[v];
            pA.x += (sA.x + accA.x) * dv; pA.y += (sA.y + accA.y) * dv;
            pA.z += (sA.z + accA.z) * dv; pA.w += (sA.w + accA.w) * dv;
            pB.x += (sB.x + accB.x) * dv; pB.y += (sB.y + accB.y) * dv;
            pB.z += (sB.z + accB.z) * dv; pB.w += (sB.w + accB.w) * dv;
        }
    }
    if (slot == 0) {
        int c0 = l * 8;
        part[ln][c0 + 0] = pA.x; part[ln][c0 + 1] = pA.y;
        part[ln][c0 + 2] = pA.z; part[ln][c0 + 3] = pA.w;
        part[ln][c0 + 4] = pB.x; part[ln][c0 + 5] = pB.y;
        part[ln][c0 + 6] = pB.z; part[ln][c0 + 7] = pB.w;
    }
    __syncthreads();
    int cnt = en - st;
    if (tid < F2) {
        float s = 0.f;
#pragma unroll 8
        for (int i = 0; i < 128; ++i) s += part[i][tid];
        gvec[tid] = (cnt > 0) ? (s / (float)cnt + b2[tid]) : 0.f;
    }
    __syncthreads();
    if (tid < F2) {
        float a = fc1b[tid];
#pragma unroll
        for (int k = 0; k < F2; ++k) a += gvec[k] * fc1w[k * F2 + tid];
        h1[tid] = fmaxf(a, 0.f);
    }
    __syncthreads();
    if (tid < F2) {
        float a = fc2b[tid];
#pragma unroll
        for (int k = 0; k < F2; ++k) a += h1[k] * fc2w[k * F2 + tid];
        out[(size_t)g * F2 + tid] = a;
    }
}

extern "C" void kernel_launch(void* const* d_in, const int* in_sizes, int n_in,
                              void* d_out, int out_size, void* d_ws, size_t ws_size,
                              hipStream_t stream) {
    const float* x    = (const float*)d_in[0];
    const int*   ei   = (const int*)d_in[1];
    const int*   batch= (const int*)d_in[2];
    const float* W1   = (const float*)d_in[3];
    const float* b1   = (const float*)d_in[4];
    const float* W2   = (const float*)d_in[5];
    const float* b2   = (const float*)d_in[6];
    const float* fc1w = (const float*)d_in[7];
    const float* fc1b = (const float*)d_in[8];
    const float* fc2w = (const float*)d_in[9];
    const float* fc2b = (const float*)d_in[10];
    float* out = (float*)d_out;

    const int N = in_sizes[0] / FIN;       // 100000
    const int E = in_sizes[1] / 2;         // 1250000
    const int G = out_size / F2;           // 512
    const int* src = ei;
    const int* dst = ei + E;
    const int NBK = (N + BNODES - 1) >> BSH;   // 196

    // ---- workspace layout (4-byte units) ----
    int* wsi = (int*)d_ws;
    int* gcur     = wsi;                   // NBK
    int* rowstart = gcur + NBK;            // N
    int* deg      = rowstart + N;          // N
    int* csr      = deg + N;               // NBK*CAPB (strided)
    unsigned* pairs = (unsigned*)(csr + (size_t)NBK * CAPB);  // NBK*CAPB (strided)
    size_t off = (size_t)NBK + 2 * (size_t)N + 2 * (size_t)NBK * CAPB;
    off = (off + 3) & ~(size_t)3;          // 16B align
    float* dinv = (float*)(wsi + off);               // N
    size_t nal = (size_t)((N + 3) & ~3);
    __half2* xnh = (__half2*)(dinv + nal);           // N*8 words (16 fp16/node)
    __half2* agg1h = (__half2*)((int*)xnh + (size_t)N * 8);  // N*8 words
    __half2* y2h = (__half2*)((int*)agg1h + (size_t)N * 8);  // N*16 words (32 fp16/node)

    const int B = 256;

    hipLaunchKernelGGL(k_initc, dim3(1), dim3(B), 0, stream, gcur, NBK);
    hipLaunchKernelGGL(k_bscatter, dim3((E + TILE - 1) / TILE), dim3(SCT), 0, stream,
                       src, dst, gcur, pairs, E, NBK);
    hipLaunchKernelGGL(k_bsort, dim3(NBK), dim3(1024), 0, stream,
                       pairs, gcur, x, rowstart, deg, dinv, csr, xnh, N);
    hipLaunchKernelGGL(k_agg1, dim3((N + 127) / 128), dim3(512), 0, stream,
                       (const uint4*)xnh, rowstart, deg, dinv, csr, (uint4*)agg1h, N);
    hipLaunchKernelGGL(k_trans, dim3((N + B - 1) / B), dim3(B), 0, stream,
                       (const uint4*)agg1h, W1, b1, W2, dinv, y2h, N);
    hipLaunchKernelGGL(k_gagg2, dim3(G), dim3(1024), 0, stream,
                       (const uint4*)y2h, rowstart, deg, dinv, csr, b2,
                       fc1w, fc1b, fc2w, fc2b, batch, out, N, G);
}

// Round 23
// 96.462 us; speedup vs baseline: 1.0853x; 1.0853x over previous
//
#include <hip/hip_runtime.h>
#include <hip/hip_fp16.h>

#define F1 64
#define F2 32
#define FIN 13
#define BSH 9                 // bucket = dst >> 9  (512 nodes/bucket)
#define BNODES 512
#define TILE 4096             // edges per scatter block (8 per thread)
#define SCT 512               // scatter threads
#define CAPB 8192             // fixed capacity per bucket (mean 6400, sd ~80 -> 22 sigma)
#define SRCMASK 0x7FFFFF      // 23-bit src (N < 8.4M)

typedef unsigned nuint4 __attribute__((ext_vector_type(4)));  // native vec for nt-store

// ---------- init capacity-strided bucket cursors ----------
__global__ void k_initc(int* __restrict__ gcur, int NBK) {
    int i = threadIdx.x + blockIdx.x * blockDim.x;
    if (i < NBK) gcur[i] = i * CAPB;
}

// ---------- partition edges into capacity-strided buckets, packed (ldst<<23|src) ----------
// register-resident edges: one vectorized read pass, histogram + scatter from regs
__global__ void __launch_bounds__(SCT)
k_bscatter(const int* __restrict__ src, const int* __restrict__ dst,
           int* __restrict__ gcur, unsigned* __restrict__ pairs,
           int E, int NBK) {
    __shared__ int lh[256];
    __shared__ int lbase[256];
    int tid = threadIdx.x;
    long t0 = (long)blockIdx.x * TILE;
    int lim = (int)min((long)TILE, (long)E - t0);
    int d[8], s[8];
    int base = tid * 8;
    if (base + 8 <= lim) {
        int4 d0 = *(const int4*)&dst[t0 + base];
        int4 d1 = *(const int4*)&dst[t0 + base + 4];
        int4 s0 = *(const int4*)&src[t0 + base];
        int4 s1 = *(const int4*)&src[t0 + base + 4];
        d[0] = d0.x; d[1] = d0.y; d[2] = d0.z; d[3] = d0.w;
        d[4] = d1.x; d[5] = d1.y; d[6] = d1.z; d[7] = d1.w;
        s[0] = s0.x; s[1] = s0.y; s[2] = s0.z; s[3] = s0.w;
        s[4] = s1.x; s[5] = s1.y; s[6] = s1.z; s[7] = s1.w;
    } else {
#pragma unroll
        for (int k = 0; k < 8; ++k) {
            int i = base + k;
            d[k] = (i < lim) ? dst[t0 + i] : -1;
            s[k] = (i < lim) ? src[t0 + i] : 0;
        }
    }
    for (int i = tid; i < NBK; i += SCT) lh[i] = 0;
    __syncthreads();
#pragma unroll
    for (int k = 0; k < 8; ++k)
        if (d[k] >= 0) atomicAdd(&lh[d[k] >> BSH], 1);
    __syncthreads();
    for (int b = tid; b < NBK; b += SCT) {
        int c = lh[b];
        lbase[b] = c ? atomicAdd(&gcur[b], c) : 0;
    }
    __syncthreads();
#pragma unroll
    for (int k = 0; k < 8; ++k) {
        if (d[k] >= 0) {
            int b = d[k] >> BSH;
            int r = atomicAdd(&lbase[b], 1);   // lbase doubles as cursor
            pairs[r] = ((unsigned)(d[k] & (BNODES - 1)) << 23) | (unsigned)s[k];
        }
    }
}

// ---------- per-bucket counting sort -> csr (strided), rowstart, deg, dinv, fused xn ----------
__global__ void __launch_bounds__(1024)
k_bsort(const unsigned* __restrict__ pairs, const int* __restrict__ gcur,
        const float* __restrict__ x, int* __restrict__ rowstart,
        int* __restrict__ deg, float* __restrict__ dinv, int* __restrict__ csr,
        __half2* __restrict__ xnh, int N) {
    __shared__ int cnt[BNODES];
    __shared__ int lex[BNODES];
    __shared__ int lcur[BNODES];
    __shared__ float dinvl[BNODES];
    __shared__ int lsorted[CAPB];
    int tid = threadIdx.x;
    int bk = blockIdx.x;
    int nodeBase = bk << BSH;
    int st = bk * CAPB;
    int m = gcur[bk] - st;
    if (m > CAPB) m = CAPB;               // safety clamp (impossible at 22 sigma)
    for (int i = tid; i < BNODES; i += 1024) { cnt[i] = 0; lcur[i] = 0; }
    __syncthreads();
    for (int i = tid; i < m; i += 1024)
        atomicAdd(&cnt[pairs[st + i] >> 23], 1);
    __syncthreads();
    if (tid < BNODES) lex[tid] = cnt[tid];
    __syncthreads();
    for (int off = 1; off < BNODES; off <<= 1) {
        int a = 0;
        if (tid < BNODES && tid >= off) a = lex[tid - off];
        __syncthreads();
        if (tid < BNODES) lex[tid] += a;
        __syncthreads();
    }
    if (tid < BNODES) {
        int ex = lex[tid] - cnt[tid];        // exclusive
        int v = nodeBase + tid;
        float dv = rsqrtf((float)(cnt[tid] + 1));
        dinvl[tid] = dv;
        if (v < N) {
            rowstart[v] = st + ex;
            deg[v] = cnt[tid];
            dinv[v] = dv;
        }
        lex[tid] = ex;
    }
    __syncthreads();
    for (int i = tid; i < m; i += 1024) {
        unsigned p = pairs[st + i];
        int ld = p >> 23;
        int r = atomicAdd(&lcur[ld], 1);
        lsorted[lex[ld] + r] = (int)(p & SRCMASK);
    }
    __syncthreads();
    for (int i = tid; i < m; i += 1024) csr[st + i] = lsorted[i];
    // fused xn: xnh[v][cp] = half2(x[v][2cp], x[v][2cp+1]) * dinv, 16 cols 0-pad
    for (int i = tid; i < BNODES * 8; i += 1024) {
        int n = i >> 3, cp = i & 7;
        int v = nodeBase + n;
        if (v < N) {
            float dv = dinvl[n];
            int c0 = 2 * cp, c1 = c0 + 1;
            float a = (c0 < FIN) ? x[(size_t)v * FIN + c0] * dv : 0.f;
            float b = (c1 < FIN) ? x[(size_t)v * FIN + c1] * dv : 0.f;
            xnh[(size_t)v * 8 + cp] = __floats2half2_rn(a, b);
        }
    }
}

__device__ __forceinline__ void acc8(const uint4& u, float4& a, float4& b) {
    float2 f0 = __half22float2(*reinterpret_cast<const __half2*>(&u.x));
    float2 f1 = __half22float2(*reinterpret_cast<const __half2*>(&u.y));
    float2 f2 = __half22float2(*reinterpret_cast<const __half2*>(&u.z));
    float2 f3 = __half22float2(*reinterpret_cast<const __half2*>(&u.w));
    a.x += f0.x; a.y += f0.y; a.z += f1.x; a.w += f1.y;
    b.x += f2.x; b.y += f2.y; b.z += f3.x; b.w += f3.y;
}

__device__ __forceinline__ unsigned packh2(float a, float b) {
    __half2 h = __floats2half2_rn(a, b);
    return *reinterpret_cast<unsigned*>(&h);
}

// ---------- layer1 pure gather: agg1h[v] = (xn[v] + sum xn[src]) * dinv, fp16 out (nt store) ----------
// 512 thr = 64 nodes x (4 slots x 2 lanes); lane reads 16B (8 fp16 cols)
__global__ void __launch_bounds__(512)
k_agg1(const uint4* __restrict__ xnh4, const int* __restrict__ rowstart,
       const int* __restrict__ deg, const float* __restrict__ dinv,
       const int* __restrict__ csr, uint4* __restrict__ agg1h4, int N) {
    int tid = threadIdx.x;
    int ln = tid >> 3;           // local node 0..63
    int slot = (tid >> 1) & 3;   // edge slot 0..3
    int l = tid & 1;             // 16B lane: cols 8l..8l+7
    int v = blockIdx.x * 64 + ln;
    if (v >= N) return;
    int st = rowstart[v];
    int en = st + deg[v];
    float4 accA = make_float4(0.f, 0.f, 0.f, 0.f);
    float4 accB = make_float4(0.f, 0.f, 0.f, 0.f);
    int e = st + slot;
    while (e + 4 < en) {         // dual-issue: 2 independent csr + 2 gathers in flight
        int s0 = csr[e];
        int s1 = csr[e + 4];
        uint4 u0 = xnh4[(size_t)s0 * 2 + l];
        uint4 u1 = xnh4[(size_t)s1 * 2 + l];
        acc8(u0, accA, accB);
        acc8(u1, accA, accB);
        e += 8;
    }
    if (e < en) {
        int s0 = csr[e];
        uint4 u0 = xnh4[(size_t)s0 * 2 + l];
        acc8(u0, accA, accB);
    }
    // reduce 4 slots (slot bits at tid[1:2])
    accA.x += __shfl_xor(accA.x, 2); accA.y += __shfl_xor(accA.y, 2);
    accA.z += __shfl_xor(accA.z, 2); accA.w += __shfl_xor(accA.w, 2);
    accB.x += __shfl_xor(accB.x, 2); accB.y += __shfl_xor(accB.y, 2);
    accB.z += __shfl_xor(accB.z, 2); accB.w += __shfl_xor(accB.w, 2);
    accA.x += __shfl_xor(accA.x, 4); accA.y += __shfl_xor(accA.y, 4);
    accA.z += __shfl_xor(accA.z, 4); accA.w += __shfl_xor(accA.w, 4);
    accB.x += __shfl_xor(accB.x, 4); accB.y += __shfl_xor(accB.y, 4);
    accB.z += __shfl_xor(accB.z, 4); accB.w += __shfl_xor(accB.w, 4);
    if (slot == 0) {
        uint4 u = xnh4[(size_t)v * 2 + l];   // self (has one dinv)
        float4 sA = make_float4(0.f, 0.f, 0.f, 0.f);
        float4 sB = make_float4(0.f, 0.f, 0.f, 0.f);
        acc8(u, sA, sB);
        float dv = dinv[v];
        nuint4 o;
        o.x = packh2((sA.x + accA.x) * dv, (sA.y + accA.y) * dv);
        o.y = packh2((sA.z + accA.z) * dv, (sA.w + accA.w) * dv);
        o.z = packh2((sB.x + accB.x) * dv, (sB.y + accB.y) * dv);
        o.w = packh2((sB.z + accB.z) * dv, (sB.w + accB.w) * dv);
        __builtin_nontemporal_store(o, (nuint4*)&agg1h4[(size_t)v * 2 + l]);
    }
}

// ---------- transform: per-node in registers. y2 = (relu(agg1@W1+b1) @ W2) * dinv ----------
__global__ void __launch_bounds__(256)
k_trans(const uint4* __restrict__ agg1h4, const float* __restrict__ W1,
        const float* __restrict__ b1, const float* __restrict__ W2,
        const float* __restrict__ dinv, __half2* __restrict__ y2h, int N) {
    int v = blockIdx.x * 256 + threadIdx.x;
    if (v >= N) return;
    uint4 u0 = agg1h4[(size_t)v * 2];
    uint4 u1 = agg1h4[(size_t)v * 2 + 1];
    float a[16];
    {
        float4 A = make_float4(0.f, 0.f, 0.f, 0.f), B = A;
        acc8(u0, A, B);
        a[0] = A.x; a[1] = A.y; a[2] = A.z; a[3] = A.w;
        a[4] = B.x; a[5] = B.y; a[6] = B.z; a[7] = B.w;
        A = make_float4(0.f, 0.f, 0.f, 0.f); B = A;
        acc8(u1, A, B);
        a[8] = A.x; a[9] = A.y; a[10] = A.z; a[11] = A.w;
        a[12] = B.x; a[13] = B.y; a[14] = B.z; a[15] = B.w;
    }
    float h[F1];
#pragma unroll
    for (int c = 0; c < F1; ++c) {
        float acc = b1[c];
#pragma unroll
        for (int k = 0; k < FIN; ++k) acc += a[k] * W1[k * F1 + c];
        h[c] = fmaxf(acc, 0.f);
    }
    float dv = dinv[v];
    for (int cp = 0; cp < 16; ++cp) {        // rolled: only acc0/acc1 live
        float acc0 = 0.f, acc1 = 0.f;
#pragma unroll
        for (int k = 0; k < F1; ++k) {       // unrolled: h[k] static
            float hv = h[k];
            acc0 += hv * W2[k * F2 + 2 * cp];
            acc1 += hv * W2[k * F2 + 2 * cp + 1];
        }
        y2h[(size_t)v * 16 + cp] = __floats2half2_rn(acc0 * dv, acc1 * dv);
    }
}

// ---------- fused layer2 aggregate + mean-pool + MLP: one block per graph ----------
// 1024 thr = 64 node-groups x (4 slots x 4 lanes); lane reads 16B (8 fp16 cols)
__global__ void __launch_bounds__(1024)
k_gagg2(const uint4* __restrict__ y2h4, const int* __restrict__ rowstart,
        const int* __restrict__ deg, const float* __restrict__ dinv,
        const int* __restrict__ csr, const float* __restrict__ b2,
        const float* __restrict__ fc1w, const float* __restrict__ fc1b,
        const float* __restrict__ fc2w, const float* __restrict__ fc2b,
        const int* __restrict__ batch, float* __restrict__ out, int N, int G) {
    __shared__ int bounds[2];
    __shared__ float part[64][33];    // pad 33: conflict-free column reduce
    __shared__ float gvec[F2];
    __shared__ float h1[F2];
    int tid = threadIdx.x;
    int g = blockIdx.x;
    if (tid < 2) {
        int target = g + tid;         // lower_bound(batch, target)
        int lo = 0, hi = N;
        while (lo < hi) {
            int mid = (lo + hi) >> 1;
            if (batch[mid] < target) lo = mid + 1; else hi = mid;
        }
        bounds[tid] = lo;
    }
    __syncthreads();
    int st = bounds[0], en = bounds[1];
    int ln = tid >> 4;            // node-group 0..63
    int slot = (tid >> 2) & 3;    // edge slot 0..3
    int l = tid & 3;              // 16B lane: cols 8l..8l+7
    float4 pA = make_float4(0.f, 0.f, 0.f, 0.f);
    float4 pB = make_float4(0.f, 0.f, 0.f, 0.f);
    for (int v = st + ln; v < en; v += 64) {
        int es = rowstart[v];
        int ee = es + deg[v];
        float4 accA = make_float4(0.f, 0.f, 0.f, 0.f);
        float4 accB = make_float4(0.f, 0.f, 0.f, 0.f);
        int e = es + slot;
        while (e + 4 < ee) {
            int s0 = csr[e];
            int s1 = csr[e + 4];
            uint4 u0 = y2h4[(size_t)s0 * 4 + l];
            uint4 u1 = y2h4[(size_t)s1 * 4 + l];
            acc8(u0, accA, accB);
            acc8(u1, accA, accB);
            e += 8;
        }
        if (e < ee) {
            int s0 = csr[e];
            uint4 u0 = y2h4[(size_t)s0 * 4 + l];
            acc8(u0, accA, accB);
        }
        // reduce 4 slots (slot bits at tid[2:3])
        accA.x += __shfl_xor(accA.x, 4); accA.y += __shfl_xor(accA.y, 4);
        accA.z += __shfl_xor(accA.z, 4); accA.w += __shfl_xor(accA.w, 4);
        accB.x += __shfl_xor(accB.x, 4); accB.y += __shfl_xor(accB.y, 4);
        accB.z += __shfl_xor(accB.z, 4); accB.w += __shfl_xor(accB.w, 4);
        accA.x += __shfl_xor(accA.x, 8); accA.y += __shfl_xor(accA.y, 8);
        accA.z += __shfl_xor(accA.z, 8); accA.w += __shfl_xor(accA.w, 8);
        accB.x += __shfl_xor(accB.x, 8); accB.y += __shfl_xor(accB.y, 8);
        accB.z += __shfl_xor(accB.z, 8); accB.w += __shfl_xor(accB.w, 8);
        if (slot == 0) {
            uint4 u = y2h4[(size_t)v * 4 + l];
            float4 sA = make_float4(0.f, 0.f, 0.f, 0.f);
            float4 sB = make_float4(0.f, 0.f, 0.f, 0.f);
            acc8(u, sA, sB);
            float dv = dinv[v];
            pA.x += (sA.x + accA.x) * dv; pA.y += (sA.y + accA.y) * dv;
            pA.z += (sA.z + accA.z) * dv; pA.w += (sA.w + accA.w) * dv;
            pB.x += (sB.x + accB.x) * dv; pB.y += (sB.y + accB.y) * dv;
            pB.z += (sB.z + accB.z) * dv; pB.w += (sB.w + accB.w) * dv;
        }
    }
    if (slot == 0) {
        int c0 = l * 8;
        part[ln][c0 + 0] = pA.x; part[ln][c0 + 1] = pA.y;
        part[ln][c0 + 2] = pA.z; part[ln][c0 + 3] = pA.w;
        part[ln][c0 + 4] = pB.x; part[ln][c0 + 5] = pB.y;
        part[ln][c0 + 6] = pB.z; part[ln][c0 + 7] = pB.w;
    }
    __syncthreads();
    int cnt = en - st;
    if (tid < F2) {
        float s = 0.f;
#pragma unroll 8
        for (int i = 0; i < 64; ++i) s += part[i][tid];
        gvec[tid] = (cnt > 0) ? (s / (float)cnt + b2[tid]) : 0.f;
    }
    __syncthreads();
    if (tid < F2) {
        float a = fc1b[tid];
#pragma unroll
        for (int k = 0; k < F2; ++k) a += gvec[k] * fc1w[k * F2 + tid];
        h1[tid] = fmaxf(a, 0.f);
    }
    __syncthreads();
    if (tid < F2) {
        float a = fc2b[tid];
#pragma unroll
        for (int k = 0; k < F2; ++k) a += h1[k] * fc2w[k * F2 + tid];
        out[(size_t)g * F2 + tid] = a;
    }
}

extern "C" void kernel_launch(void* const* d_in, const int* in_sizes, int n_in,
                              void* d_out, int out_size, void* d_ws, size_t ws_size,
                              hipStream_t stream) {
    const float* x    = (const float*)d_in[0];
    const int*   ei   = (const int*)d_in[1];
    const int*   batch= (const int*)d_in[2];
    const float* W1   = (const float*)d_in[3];
    const float* b1   = (const float*)d_in[4];
    const float* W2   = (const float*)d_in[5];
    const float* b2   = (const float*)d_in[6];
    const float* fc1w = (const float*)d_in[7];
    const float* fc1b = (const float*)d_in[8];
    const float* fc2w = (const float*)d_in[9];
    const float* fc2b = (const float*)d_in[10];
    float* out = (float*)d_out;

    const int N = in_sizes[0] / FIN;       // 100000
    const int E = in_sizes[1] / 2;         // 1250000
    const int G = out_size / F2;           // 512
    const int* src = ei;
    const int* dst = ei + E;
    const int NBK = (N + BNODES - 1) >> BSH;   // 196

    // ---- workspace layout (4-byte units) ----
    int* wsi = (int*)d_ws;
    int* gcur     = wsi;                   // NBK
    int* rowstart = gcur + NBK;            // N
    int* deg      = rowstart + N;          // N
    int* csr      = deg + N;               // NBK*CAPB (strided)
    unsigned* pairs = (unsigned*)(csr + (size_t)NBK * CAPB);  // NBK*CAPB (strided)
    size_t off = (size_t)NBK + 2 * (size_t)N + 2 * (size_t)NBK * CAPB;
    off = (off + 3) & ~(size_t)3;          // 16B align
    float* dinv = (float*)(wsi + off);               // N
    size_t nal = (size_t)((N + 3) & ~3);
    __half2* xnh = (__half2*)(dinv + nal);           // N*8 words (16 fp16/node)
    __half2* agg1h = (__half2*)((int*)xnh + (size_t)N * 8);  // N*8 words
    __half2* y2h = (__half2*)((int*)agg1h + (size_t)N * 8);  // N*16 words (32 fp16/node)

    const int B = 256;

    hipLaunchKernelGGL(k_initc, dim3(1), dim3(B), 0, stream, gcur, NBK);
    hipLaunchKernelGGL(k_bscatter, dim3((E + TILE - 1) / TILE), dim3(SCT), 0, stream,
                       src, dst, gcur, pairs, E, NBK);
    hipLaunchKernelGGL(k_bsort, dim3(NBK), dim3(1024), 0, stream,
                       pairs, gcur, x, rowstart, deg, dinv, csr, xnh, N);
    hipLaunchKernelGGL(k_agg1, dim3((N + 63) / 64), dim3(512), 0, stream,
                       (const uint4*)xnh, rowstart, deg, dinv, csr, (uint4*)agg1h, N);
    hipLaunchKernelGGL(k_trans, dim3((N + B - 1) / B), dim3(B), 0, stream,
                       (const uint4*)agg1h, W1, b1, W2, dinv, y2h, N);
    hipLaunchKernelGGL(k_gagg2, dim3(G), dim3(1024), 0, stream,
                       (const uint4*)y2h, rowstart, deg, dinv, csr, b2,
                       fc1w, fc1b, fc2w, fc2b, batch, out, N, G);
}

// Round 24
// 96.178 us; speedup vs baseline: 1.0885x; 1.0030x over previous
//
#include <hip/hip_runtime.h>
#include <hip/hip_fp16.h>

#define F1 64
#define F2 32
#define FIN 13
#define BSH 9                 // bucket = dst >> 9  (512 nodes/bucket)
#define BNODES 512
#define TILE 4096             // edges per scatter block (8 per thread)
#define SCT 512               // scatter threads
#define CAPB 8192             // fixed capacity per bucket (mean 6400, sd ~80 -> 22 sigma)
#define SRCMASK 0x7FFFFF      // 23-bit src (N < 8.4M)

typedef unsigned nuint4 __attribute__((ext_vector_type(4)));  // native vec for nt-store

// ---------- init capacity-strided bucket cursors ----------
__global__ void k_initc(int* __restrict__ gcur, int NBK) {
    int i = threadIdx.x + blockIdx.x * blockDim.x;
    if (i < NBK) gcur[i] = i * CAPB;
}

// ---------- partition edges into capacity-strided buckets, packed (ldst<<23|src) ----------
// register-resident edges: one vectorized read pass, histogram + scatter from regs
__global__ void __launch_bounds__(SCT)
k_bscatter(const int* __restrict__ src, const int* __restrict__ dst,
           int* __restrict__ gcur, unsigned* __restrict__ pairs,
           int E, int NBK) {
    __shared__ int lh[256];
    __shared__ int lbase[256];
    int tid = threadIdx.x;
    long t0 = (long)blockIdx.x * TILE;
    int lim = (int)min((long)TILE, (long)E - t0);
    int d[8], s[8];
    int base = tid * 8;
    if (base + 8 <= lim) {
        int4 d0 = *(const int4*)&dst[t0 + base];
        int4 d1 = *(const int4*)&dst[t0 + base + 4];
        int4 s0 = *(const int4*)&src[t0 + base];
        int4 s1 = *(const int4*)&src[t0 + base + 4];
        d[0] = d0.x; d[1] = d0.y; d[2] = d0.z; d[3] = d0.w;
        d[4] = d1.x; d[5] = d1.y; d[6] = d1.z; d[7] = d1.w;
        s[0] = s0.x; s[1] = s0.y; s[2] = s0.z; s[3] = s0.w;
        s[4] = s1.x; s[5] = s1.y; s[6] = s1.z; s[7] = s1.w;
    } else {
#pragma unroll
        for (int k = 0; k < 8; ++k) {
            int i = base + k;
            d[k] = (i < lim) ? dst[t0 + i] : -1;
            s[k] = (i < lim) ? src[t0 + i] : 0;
        }
    }
    for (int i = tid; i < NBK; i += SCT) lh[i] = 0;
    __syncthreads();
#pragma unroll
    for (int k = 0; k < 8; ++k)
        if (d[k] >= 0) atomicAdd(&lh[d[k] >> BSH], 1);
    __syncthreads();
    for (int b = tid; b < NBK; b += SCT) {
        int c = lh[b];
        lbase[b] = c ? atomicAdd(&gcur[b], c) : 0;
    }
    __syncthreads();
#pragma unroll
    for (int k = 0; k < 8; ++k) {
        if (d[k] >= 0) {
            int b = d[k] >> BSH;
            int r = atomicAdd(&lbase[b], 1);   // lbase doubles as cursor
            pairs[r] = ((unsigned)(d[k] & (BNODES - 1)) << 23) | (unsigned)s[k];
        }
    }
}

// ---------- per-bucket counting sort -> csr (strided), rowstart, deg, dinv, fused xn ----------
__global__ void __launch_bounds__(1024)
k_bsort(const unsigned* __restrict__ pairs, const int* __restrict__ gcur,
        const float* __restrict__ x, int* __restrict__ rowstart,
        int* __restrict__ deg, float* __restrict__ dinv, int* __restrict__ csr,
        __half2* __restrict__ xnh, int N) {
    __shared__ int cnt[BNODES];
    __shared__ int lex[BNODES];
    __shared__ int lcur[BNODES];
    __shared__ float dinvl[BNODES];
    __shared__ int lsorted[CAPB];
    int tid = threadIdx.x;
    int bk = blockIdx.x;
    int nodeBase = bk << BSH;
    int st = bk * CAPB;
    int m = gcur[bk] - st;
    if (m > CAPB) m = CAPB;               // safety clamp (impossible at 22 sigma)
    for (int i = tid; i < BNODES; i += 1024) { cnt[i] = 0; lcur[i] = 0; }
    __syncthreads();
    for (int i = tid; i < m; i += 1024)
        atomicAdd(&cnt[pairs[st + i] >> 23], 1);
    __syncthreads();
    if (tid < BNODES) lex[tid] = cnt[tid];
    __syncthreads();
    for (int off = 1; off < BNODES; off <<= 1) {
        int a = 0;
        if (tid < BNODES && tid >= off) a = lex[tid - off];
        __syncthreads();
        if (tid < BNODES) lex[tid] += a;
        __syncthreads();
    }
    if (tid < BNODES) {
        int ex = lex[tid] - cnt[tid];        // exclusive
        int v = nodeBase + tid;
        float dv = rsqrtf((float)(cnt[tid] + 1));
        dinvl[tid] = dv;
        if (v < N) {
            rowstart[v] = st + ex;
            deg[v] = cnt[tid];
            dinv[v] = dv;
        }
        lex[tid] = ex;
    }
    __syncthreads();
    for (int i = tid; i < m; i += 1024) {
        unsigned p = pairs[st + i];
        int ld = p >> 23;
        int r = atomicAdd(&lcur[ld], 1);
        lsorted[lex[ld] + r] = (int)(p & SRCMASK);
    }
    __syncthreads();
    for (int i = tid; i < m; i += 1024) csr[st + i] = lsorted[i];
    // fused xn: xnh[v][cp] = half2(x[v][2cp], x[v][2cp+1]) * dinv, 16 cols 0-pad
    for (int i = tid; i < BNODES * 8; i += 1024) {
        int n = i >> 3, cp = i & 7;
        int v = nodeBase + n;
        if (v < N) {
            float dv = dinvl[n];
            int c0 = 2 * cp, c1 = c0 + 1;
            float a = (c0 < FIN) ? x[(size_t)v * FIN + c0] * dv : 0.f;
            float b = (c1 < FIN) ? x[(size_t)v * FIN + c1] * dv : 0.f;
            xnh[(size_t)v * 8 + cp] = __floats2half2_rn(a, b);
        }
    }
}

__device__ __forceinline__ void acc8(const uint4& u, float4& a, float4& b) {
    float2 f0 = __half22float2(*reinterpret_cast<const __half2*>(&u.x));
    float2 f1 = __half22float2(*reinterpret_cast<const __half2*>(&u.y));
    float2 f2 = __half22float2(*reinterpret_cast<const __half2*>(&u.z));
    float2 f3 = __half22float2(*reinterpret_cast<const __half2*>(&u.w));
    a.x += f0.x; a.y += f0.y; a.z += f1.x; a.w += f1.y;
    b.x += f2.x; b.y += f2.y; b.z += f3.x; b.w += f3.y;
}

__device__ __forceinline__ unsigned packh2(float a, float b) {
    __half2 h = __floats2half2_rn(a, b);
    return *reinterpret_cast<unsigned*>(&h);
}

// ---------- layer1 pure gather: agg1h[v] = (xn[v] + sum xn[src]) * dinv, fp16 out (nt store) ----------
// 512 thr = 64 nodes x (4 slots x 2 lanes); lane reads 16B (8 fp16 cols)
__global__ void __launch_bounds__(512)
k_agg1(const uint4* __restrict__ xnh4, const int* __restrict__ rowstart,
       const int* __restrict__ deg, const float* __restrict__ dinv,
       const int* __restrict__ csr, uint4* __restrict__ agg1h4, int N) {
    int tid = threadIdx.x;
    int ln = tid >> 3;           // local node 0..63
    int slot = (tid >> 1) & 3;   // edge slot 0..3
    int l = tid & 1;             // 16B lane: cols 8l..8l+7
    int v = blockIdx.x * 64 + ln;
    if (v >= N) return;
    int st = rowstart[v];
    int en = st + deg[v];
    float4 accA = make_float4(0.f, 0.f, 0.f, 0.f);
    float4 accB = make_float4(0.f, 0.f, 0.f, 0.f);
    int e = st + slot;
    while (e + 4 < en) {         // dual-issue: 2 independent csr + 2 gathers in flight
        int s0 = csr[e];
        int s1 = csr[e + 4];
        uint4 u0 = xnh4[(size_t)s0 * 2 + l];
        uint4 u1 = xnh4[(size_t)s1 * 2 + l];
        acc8(u0, accA, accB);
        acc8(u1, accA, accB);
        e += 8;
    }
    if (e < en) {
        int s0 = csr[e];
        uint4 u0 = xnh4[(size_t)s0 * 2 + l];
        acc8(u0, accA, accB);
    }
    // reduce 4 slots (slot bits at tid[1:2])
    accA.x += __shfl_xor(accA.x, 2); accA.y += __shfl_xor(accA.y, 2);
    accA.z += __shfl_xor(accA.z, 2); accA.w += __shfl_xor(accA.w, 2);
    accB.x += __shfl_xor(accB.x, 2); accB.y += __shfl_xor(accB.y, 2);
    accB.z += __shfl_xor(accB.z, 2); accB.w += __shfl_xor(accB.w, 2);
    accA.x += __shfl_xor(accA.x, 4); accA.y += __shfl_xor(accA.y, 4);
    accA.z += __shfl_xor(accA.z, 4); accA.w += __shfl_xor(accA.w, 4);
    accB.x += __shfl_xor(accB.x, 4); accB.y += __shfl_xor(accB.y, 4);
    accB.z += __shfl_xor(accB.z, 4); accB.w += __shfl_xor(accB.w, 4);
    if (slot == 0) {
        uint4 u = xnh4[(size_t)v * 2 + l];   // self (has one dinv)
        float4 sA = make_float4(0.f, 0.f, 0.f, 0.f);
        float4 sB = make_float4(0.f, 0.f, 0.f, 0.f);
        acc8(u, sA, sB);
        float dv = dinv[v];
        nuint4 o;
        o.x = packh2((sA.x + accA.x) * dv, (sA.y + accA.y) * dv);
        o.y = packh2((sA.z + accA.z) * dv, (sA.w + accA.w) * dv);
        o.z = packh2((sB.x + accB.x) * dv, (sB.y + accB.y) * dv);
        o.w = packh2((sB.z + accB.z) * dv, (sB.w + accB.w) * dv);
        __builtin_nontemporal_store(o, (nuint4*)&agg1h4[(size_t)v * 2 + l]);
    }
}

// ---------- transform: per-node in registers. y2 = (relu(agg1@W1+b1) @ W2) * dinv ----------
__global__ void __launch_bounds__(256)
k_trans(const uint4* __restrict__ agg1h4, const float* __restrict__ W1,
        const float* __restrict__ b1, const float* __restrict__ W2,
        const float* __restrict__ dinv, __half2* __restrict__ y2h, int N) {
    int v = blockIdx.x * 256 + threadIdx.x;
    if (v >= N) return;
    uint4 u0 = agg1h4[(size_t)v * 2];
    uint4 u1 = agg1h4[(size_t)v * 2 + 1];
    float a[16];
    {
        float4 A = make_float4(0.f, 0.f, 0.f, 0.f), B = A;
        acc8(u0, A, B);
        a[0] = A.x; a[1] = A.y; a[2] = A.z; a[3] = A.w;
        a[4] = B.x; a[5] = B.y; a[6] = B.z; a[7] = B.w;
        A = make_float4(0.f, 0.f, 0.f, 0.f); B = A;
        acc8(u1, A, B);
        a[8] = A.x; a[9] = A.y; a[10] = A.z; a[11] = A.w;
        a[12] = B.x; a[13] = B.y; a[14] = B.z; a[15] = B.w;
    }
    float h[F1];
#pragma unroll
    for (int c = 0; c < F1; ++c) {
        float acc = b1[c];
#pragma unroll
        for (int k = 0; k < FIN; ++k) acc += a[k] * W1[k * F1 + c];
        h[c] = fmaxf(acc, 0.f);
    }
    float dv = dinv[v];
    for (int cp = 0; cp < 16; ++cp) {        // rolled: only acc0/acc1 live
        float acc0 = 0.f, acc1 = 0.f;
#pragma unroll
        for (int k = 0; k < F1; ++k) {       // unrolled: h[k] static
            float hv = h[k];
            acc0 += hv * W2[k * F2 + 2 * cp];
            acc1 += hv * W2[k * F2 + 2 * cp + 1];
        }
        y2h[(size_t)v * 16 + cp] = __floats2half2_rn(acc0 * dv, acc1 * dv);
    }
}

// ---------- fused layer2 aggregate + mean-pool + MLP: one block per graph ----------
// 1024 thr = 64 node-groups x (4 slots x 4 lanes); lane reads 16B (8 fp16 cols)
__global__ void __launch_bounds__(1024)
k_gagg2(const uint4* __restrict__ y2h4, const int* __restrict__ rowstart,
        const int* __restrict__ deg, const float* __restrict__ dinv,
        const int* __restrict__ csr, const float* __restrict__ b2,
        const float* __restrict__ fc1w, const float* __restrict__ fc1b,
        const float* __restrict__ fc2w, const float* __restrict__ fc2b,
        const int* __restrict__ batch, float* __restrict__ out, int N, int G) {
    __shared__ int bounds[2];
    __shared__ float part[64][33];    // pad 33: conflict-free column reduce
    __shared__ float gvec[F2];
    __shared__ float h1[F2];
    int tid = threadIdx.x;
    int g = blockIdx.x;
    if (tid < 2) {
        int target = g + tid;         // lower_bound(batch, target)
        int lo = 0, hi = N;
        while (lo < hi) {
            int mid = (lo + hi) >> 1;
            if (batch[mid] < target) lo = mid + 1; else hi = mid;
        }
        bounds[tid] = lo;
    }
    __syncthreads();
    int st = bounds[0], en = bounds[1];
    int ln = tid >> 4;            // node-group 0..63
    int slot = (tid >> 2) & 3;    // edge slot 0..3
    int l = tid & 3;              // 16B lane: cols 8l..8l+7
    float4 pA = make_float4(0.f, 0.f, 0.f, 0.f);
    float4 pB = make_float4(0.f, 0.f, 0.f, 0.f);
    for (int v = st + ln; v < en; v += 64) {
        int es = rowstart[v];
        int ee = es + deg[v];
        float4 accA = make_float4(0.f, 0.f, 0.f, 0.f);
        float4 accB = make_float4(0.f, 0.f, 0.f, 0.f);
        int e = es + slot;
        while (e + 4 < ee) {
            int s0 = csr[e];
            int s1 = csr[e + 4];
            uint4 u0 = y2h4[(size_t)s0 * 4 + l];
            uint4 u1 = y2h4[(size_t)s1 * 4 + l];
            acc8(u0, accA, accB);
            acc8(u1, accA, accB);
            e += 8;
        }
        if (e < ee) {
            int s0 = csr[e];
            uint4 u0 = y2h4[(size_t)s0 * 4 + l];
            acc8(u0, accA, accB);
        }
        // reduce 4 slots (slot bits at tid[2:3])
        accA.x += __shfl_xor(accA.x, 4); accA.y += __shfl_xor(accA.y, 4);
        accA.z += __shfl_xor(accA.z, 4); accA.w += __shfl_xor(accA.w, 4);
        accB.x += __shfl_xor(accB.x, 4); accB.y += __shfl_xor(accB.y, 4);
        accB.z += __shfl_xor(accB.z, 4); accB.w += __shfl_xor(accB.w, 4);
        accA.x += __shfl_xor(accA.x, 8); accA.y += __shfl_xor(accA.y, 8);
        accA.z += __shfl_xor(accA.z, 8); accA.w += __shfl_xor(accA.w, 8);
        accB.x += __shfl_xor(accB.x, 8); accB.y += __shfl_xor(accB.y, 8);
        accB.z += __shfl_xor(accB.z, 8); accB.w += __shfl_xor(accB.w, 8);
        if (slot == 0) {
            uint4 u = y2h4[(size_t)v * 4 + l];
            float4 sA = make_float4(0.f, 0.f, 0.f, 0.f);
            float4 sB = make_float4(0.f, 0.f, 0.f, 0.f);
            acc8(u, sA, sB);
            float dv = dinv[v];
            pA.x += (sA.x + accA.x) * dv; pA.y += (sA.y + accA.y) * dv;
            pA.z += (sA.z + accA.z) * dv; pA.w += (sA.w + accA.w) * dv;
            pB.x += (sB.x + accB.x) * dv; pB.y += (sB.y + accB.y) * dv;
            pB.z += (sB.z + accB.z) * dv; pB.w += (sB.w + accB.w) * dv;
        }
    }
    if (slot == 0) {
        int c0 = l * 8;
        part[ln][c0 + 0] = pA.x; part[ln][c0 + 1] = pA.y;
        part[ln][c0 + 2] = pA.z; part[ln][c0 + 3] = pA.w;
        part[ln][c0 + 4] = pB.x; part[ln][c0 + 5] = pB.y;
        part[ln][c0 + 6] = pB.z; part[ln][c0 + 7] = pB.w;
    }
    __syncthreads();
    int cnt = en - st;
    if (tid < F2) {
        float s = 0.f;
#pragma unroll 8
        for (int i = 0; i < 64; ++i) s += part[i][tid];
        gvec[tid] = (cnt > 0) ? (s / (float)cnt + b2[tid]) : 0.f;
    }
    __syncthreads();
    if (tid < F2) {
        float a = fc1b[tid];
#pragma unroll
        for (int k = 0; k < F2; ++k) a += gvec[k] * fc1w[k * F2 + tid];
        h1[tid] = fmaxf(a, 0.f);
    }
    __syncthreads();
    if (tid < F2) {
        float a = fc2b[tid];
#pragma unroll
        for (int k = 0; k < F2; ++k) a += h1[k] * fc2w[k * F2 + tid];
        out[(size_t)g * F2 + tid] = a;
    }
}

extern "C" void kernel_launch(void* const* d_in, const int* in_sizes, int n_in,
                              void* d_out, int out_size, void* d_ws, size_t ws_size,
                              hipStream_t stream) {
    const float* x    = (const float*)d_in[0];
    const int*   ei   = (const int*)d_in[1];
    const int*   batch= (const int*)d_in[2];
    const float* W1   = (const float*)d_in[3];
    const float* b1   = (const float*)d_in[4];
    const float* W2   = (const float*)d_in[5];
    const float* b2   = (const float*)d_in[6];
    const float* fc1w = (const float*)d_in[7];
    const float* fc1b = (const float*)d_in[8];
    const float* fc2w = (const float*)d_in[9];
    const float* fc2b = (const float*)d_in[10];
    float* out = (float*)d_out;

    const int N = in_sizes[0] / FIN;       // 100000
    const int E = in_sizes[1] / 2;         // 1250000
    const int G = out_size / F2;           // 512
    const int* src = ei;
    const int* dst = ei + E;
    const int NBK = (N + BNODES - 1) >> BSH;   // 196

    // ---- workspace layout (4-byte units) ----
    int* wsi = (int*)d_ws;
    int* gcur     = wsi;                   // NBK
    int* rowstart = gcur + NBK;            // N
    int* deg      = rowstart + N;          // N
    int* csr      = deg + N;               // NBK*CAPB (strided)
    unsigned* pairs = (unsigned*)(csr + (size_t)NBK * CAPB);  // NBK*CAPB (strided)
    size_t off = (size_t)NBK + 2 * (size_t)N + 2 * (size_t)NBK * CAPB;
    off = (off + 3) & ~(size_t)3;          // 16B align
    float* dinv = (float*)(wsi + off);               // N
    size_t nal = (size_t)((N + 3) & ~3);
    __half2* xnh = (__half2*)(dinv + nal);           // N*8 words (16 fp16/node)
    __half2* agg1h = (__half2*)((int*)xnh + (size_t)N * 8);  // N*8 words
    __half2* y2h = (__half2*)((int*)agg1h + (size_t)N * 8);  // N*16 words (32 fp16/node)

    const int B = 256;

    hipLaunchKernelGGL(k_initc, dim3(1), dim3(B), 0, stream, gcur, NBK);
    hipLaunchKernelGGL(k_bscatter, dim3((E + TILE - 1) / TILE), dim3(SCT), 0, stream,
                       src, dst, gcur, pairs, E, NBK);
    hipLaunchKernelGGL(k_bsort, dim3(NBK), dim3(1024), 0, stream,
                       pairs, gcur, x, rowstart, deg, dinv, csr, xnh, N);
    hipLaunchKernelGGL(k_agg1, dim3((N + 63) / 64), dim3(512), 0, stream,
                       (const uint4*)xnh, rowstart, deg, dinv, csr, (uint4*)agg1h, N);
    hipLaunchKernelGGL(k_trans, dim3((N + B - 1) / B), dim3(B), 0, stream,
                       (const uint4*)agg1h, W1, b1, W2, dinv, y2h, N);
    hipLaunchKernelGGL(k_gagg2, dim3(G), dim3(1024), 0, stream,
                       (const uint4*)y2h, rowstart, deg, dinv, csr, b2,
                       fc1w, fc1b, fc2w, fc2b, batch, out, N, G);
}